// Round 1
// baseline (109.492 us; speedup 1.0000x reference)
//
#include <hip/hip_runtime.h>

#define IMH 512
#define IMW 512
#define TW 32
#define TH 8
#define HW_ (TW + 2)          // 34
#define HH_ (TH + 2)          // 10
#define NHALO (HW_ * HH_)     // 340
#define ROW 31                // padded floats per halo pixel (30 channels + 1 pad; gcd(31,32)=1)

// Fused: stage A (pointwise Bayes update + sensitivity quotient rule) -> LDS,
// stage B (3x3 conv x 10 channel-groups + softmax + softmax-JVP) -> global.
__global__ __launch_bounds__(256, 2)
void hmm_fused(const float* __restrict__ obs,
               const float* __restrict__ P,      // (S,O) indexed P[o*3+s] per einsum 'os,hwo->hws'
               const float* __restrict__ u_k,
               const float* __restrict__ w_k,    // (H,W,S,1,S,O) -> pix*27 + s*9 + i*3 + j
               const float* __restrict__ conv_w, // (S_out,S_in,3,3)
               const float* __restrict__ conv_b, // (S,)
               float* __restrict__ out) {        // [0, 512*512*3): u_kp1 ; rest: w_kp1_O
    __shared__ float lds[NHALO * ROW];           // 42,160 B; reused for w-output staging

    const int tid = threadIdx.x;
    const int w0 = blockIdx.x * TW;
    const int h0 = blockIdx.y * TH;

    // P into registers (wave-uniform)
    float Pm[9];
#pragma unroll
    for (int i = 0; i < 9; ++i) Pm[i] = P[i];

    // ---------- Stage A: halo pixels -> Z (group 0) and w_pre (groups 1..9) in LDS
    for (int p = tid; p < NHALO; p += 256) {
        const int hh = h0 + p / HW_ - 1;
        const int ww = w0 + p % HW_ - 1;
        float* row = &lds[p * ROW];
        if (hh < 0 || hh >= IMH || ww < 0 || ww >= IMW) {
#pragma unroll
            for (int c = 0; c < 30; ++c) row[c] = 0.0f;   // SAME zero padding
            continue;
        }
        const int pix = hh * IMW + ww;
        const float ov[3] = {obs[pix * 3 + 0], obs[pix * 3 + 1], obs[pix * 3 + 2]};
        const float us[3] = {u_k[pix * 3 + 0], u_k[pix * 3 + 1], u_k[pix * 3 + 2]};

        float b[3], Bu[3], bu = 0.0f;
#pragma unroll
        for (int s = 0; s < 3; ++s) {
            b[s] = Pm[0 * 3 + s] * ov[0] + Pm[1 * 3 + s] * ov[1] + Pm[2 * 3 + s] * ov[2];
            Bu[s] = b[s] * us[s];
            bu += Bu[s];
        }
        const float inv_bu = 1.0f / bu;
        float Z[3];
#pragma unroll
        for (int s = 0; s < 3; ++s) { Z[s] = Bu[s] * inv_bu; row[s] = Z[s]; }

        const float* wkp = &w_k[(size_t)pix * 27];
#pragma unroll
        for (int i = 0; i < 3; ++i) {
#pragma unroll
            for (int j = 0; j < 3; ++j) {
                const int ij = i * 3 + j;
                float du[3], sdu = 0.0f;
#pragma unroll
                for (int s = 0; s < 3; ++s) {
                    float d = b[s] * wkp[s * 9 + ij];
                    if (s == j) d += ov[i] * us[s];
                    du[s] = d;
                    sdu += d;
                }
#pragma unroll
                for (int s = 0; s < 3; ++s)
                    row[(1 + ij) * 3 + s] = (du[s] - sdu * Z[s]) * inv_bu;  // (du*bu - sdu*Bu)/bu^2
            }
        }
    }

    // conv weights/bias (wave-uniform loads)
    float cw[81];
#pragma unroll
    for (int i = 0; i < 81; ++i) cw[i] = conv_w[i];
    const float cb[3] = {conv_b[0], conv_b[1], conv_b[2]};

    __syncthreads();

    // ---------- Stage B: one interior pixel per thread
    const int tx = tid % TW, ty = tid / TW;
    const int hp = (ty + 1) * HW_ + (tx + 1);
    const int pix = (h0 + ty) * IMW + (w0 + tx);

    // group 0: y = conv(Z)+b -> softmax
    float p0, p1, p2;
    {
        float y[3] = {cb[0], cb[1], cb[2]};
#pragma unroll
        for (int ky = 0; ky < 3; ++ky) {
#pragma unroll
            for (int kx = 0; kx < 3; ++kx) {
                const float* nb = &lds[(hp + (ky - 1) * HW_ + (kx - 1)) * ROW];
                const float v0 = nb[0], v1 = nb[1], v2 = nb[2];
#pragma unroll
                for (int s = 0; s < 3; ++s)
                    y[s] += cw[s * 27 + 0 * 9 + ky * 3 + kx] * v0 +
                            cw[s * 27 + 1 * 9 + ky * 3 + kx] * v1 +
                            cw[s * 27 + 2 * 9 + ky * 3 + kx] * v2;
            }
        }
        const float m = fmaxf(y[0], fmaxf(y[1], y[2]));
        const float e0 = __expf(y[0] - m), e1 = __expf(y[1] - m), e2 = __expf(y[2] - m);
        const float inv = 1.0f / (e0 + e1 + e2);
        p0 = e0 * inv; p1 = e1 * inv; p2 = e2 * inv;
        out[pix * 3 + 0] = p0; out[pix * 3 + 1] = p1; out[pix * 3 + 2] = p2;
    }

    // groups 1..9: a = conv(w_pre_g); w_out = p*(a - <p,a>)   (softmax JVP)
    float wout[27];
#pragma unroll
    for (int g = 1; g < 10; ++g) {
        float a[3] = {0.0f, 0.0f, 0.0f};
#pragma unroll
        for (int ky = 0; ky < 3; ++ky) {
#pragma unroll
            for (int kx = 0; kx < 3; ++kx) {
                const float* nb = &lds[(hp + (ky - 1) * HW_ + (kx - 1)) * ROW];
                const float v0 = nb[g * 3 + 0], v1 = nb[g * 3 + 1], v2 = nb[g * 3 + 2];
#pragma unroll
                for (int s = 0; s < 3; ++s)
                    a[s] += cw[s * 27 + 0 * 9 + ky * 3 + kx] * v0 +
                            cw[s * 27 + 1 * 9 + ky * 3 + kx] * v1 +
                            cw[s * 27 + 2 * 9 + ky * 3 + kx] * v2;
            }
        }
        const float dot = p0 * a[0] + p1 * a[1] + p2 * a[2];
        const int ij = g - 1;
        wout[0 * 9 + ij] = p0 * (a[0] - dot);
        wout[1 * 9 + ij] = p1 * (a[1] - dot);
        wout[2 * 9 + ij] = p2 * (a[2] - dot);
    }

    __syncthreads();   // all zw reads done; LDS can be reused

    // stage w-output in LDS so global stores are fully coalesced.
    // lds flat index == tile-local output flat index: (ty*TW+tx)*27 + c = ty*864 + (tx*27+c)
#pragma unroll
    for (int c = 0; c < 27; ++c) lds[tid * 27 + c] = wout[c];
    __syncthreads();

    float* outw = out + IMH * IMW * 3;
    for (int idx = tid; idx < TW * TH * 27; idx += 256) {
        const int r = idx / (TW * 27);
        const int rem = idx - r * (TW * 27);
        outw[(h0 + r) * (IMW * 27) + w0 * 27 + rem] = lds[idx];
    }
}

extern "C" void kernel_launch(void* const* d_in, const int* in_sizes, int n_in,
                              void* d_out, int out_size, void* d_ws, size_t ws_size,
                              hipStream_t stream) {
    const float* obs    = (const float*)d_in[0];
    const float* P      = (const float*)d_in[1];
    const float* u_k    = (const float*)d_in[2];
    const float* w_k    = (const float*)d_in[3];
    const float* conv_w = (const float*)d_in[4];
    const float* conv_b = (const float*)d_in[5];
    float* out = (float*)d_out;

    dim3 grid(IMW / TW, IMH / TH);   // (16, 64)
    hmm_fused<<<grid, 256, 0, stream>>>(obs, P, u_k, w_k, conv_w, conv_b, out);
}